// Round 2
// baseline (2499.137 us; speedup 1.0000x reference)
//
#include <hip/hip_runtime.h>
#include <hip/hip_bf16.h>

#define N_NODES  100000
#define N_GRAPHS 512
#define IN_CH    128
#define HID      32
#define OUT_CH   10
#define N_EDGES  3200000

#define BW       64                      // nodes per bucket
#define NB       ((N_NODES + BW - 1) / BW)   // 1563
#define CAP      2560                    // mean 2048, +11 sigma
#define ASTRIDE  33                      // padded LDS stride (bank-conflict fix)

// ---- int32/int64 index loader (low word of little-endian int64) ----
__device__ __forceinline__ int load_idx(const int* __restrict__ p, long long pos, int is64) {
  return is64 ? p[2 * pos] : p[(int)pos];
}

// Detect whether index buffers are int64: if int64, the high words of the
// first 4096 entries (values < 2^31) are all zero; if int32, these words are
// random node ids (~surely nonzero).
__global__ void detect_i64(const int* __restrict__ ei, int* __restrict__ flag) {
  __shared__ int any_nz;
  if (threadIdx.x == 0) any_nz = 0;
  __syncthreads();
  for (int i = threadIdx.x; i < 4096; i += 256) {
    if (ei[2 * i + 1] != 0) any_nz = 1;
  }
  __syncthreads();
  if (threadIdx.x == 0) flag[0] = any_nz ? 0 : 1;
}

// ---- pass 1: bucket edges by dst>>6; store packed (src<<6 | dst&63) ----
__global__ void bucket_k(const int* __restrict__ ei, const int* __restrict__ flag,
                         int* __restrict__ bcnt, int* __restrict__ bstore) {
  int e = blockIdx.x * 256 + threadIdx.x;
  if (e >= N_EDGES) return;
  int is64 = flag[0];
  int s = load_idx(ei, (long long)e, is64);
  int d = load_idx(ei, (long long)N_EDGES + e, is64);
  int b = d >> 6;
  int pos = atomicAdd(&bcnt[b], 1);
  if (pos < CAP) bstore[(size_t)b * CAP + pos] = (s << 6) | (d & 63);
}

// ---- per-bucket LDS degree histogram -> dinv ----
__global__ void dinv_bucket_k(const int* __restrict__ bstore, const int* __restrict__ bcnt,
                              float* __restrict__ dinv) {
  __shared__ int h[BW];
  int b = blockIdx.x, t = threadIdx.x;
  if (t < BW) h[t] = 0;
  __syncthreads();
  int cnt = min(bcnt[b], CAP);
  const int* eb = bstore + (size_t)b * CAP;
  for (int i = t; i < cnt; i += 256) atomicAdd(&h[eb[i] & 63], 1);
  __syncthreads();
  int node = b * BW + t;
  if (t < BW && node < N_NODES) dinv[node] = rsqrtf((float)(h[t] + 1));  // +1 self-loop
}

// ---- G = (X @ W) * dinv[row] ;  X:[n,K], W:[K,32] ----
template <int K>
__global__ void gemm_scale(const float* __restrict__ X, const float* __restrict__ W,
                           const float* __restrict__ dinv, float* __restrict__ G,
                           int nrows) {
  __shared__ float Ws[K * HID];
  __shared__ float Xs[8 * K];
  for (int i = threadIdx.x; i < K * HID; i += 256) Ws[i] = W[i];
  int c = threadIdx.x & 31, r = threadIdx.x >> 5;
  int ntiles = nrows / 8;
  for (int tile = blockIdx.x; tile < ntiles; tile += gridDim.x) {
    int row0 = tile * 8;
    __syncthreads();
    for (int i = threadIdx.x; i < 8 * K; i += 256) Xs[i] = X[row0 * K + i];
    __syncthreads();
    int row = row0 + r;
    float acc = 0.f;
#pragma unroll
    for (int k = 0; k < K; k++) acc += Xs[r * K + k] * Ws[k * 32 + c];
    G[row * 32 + c] = acc * dinv[row];
  }
}

// ---- push-aggregate one bucket in LDS:
//      out[d] = act( dinv[d] * (sum_{src in N(d)} g[src] + g[d]) + b ) ----
__global__ void agg_bucket(const float* __restrict__ g, const int* __restrict__ bstore,
                           const int* __restrict__ bcnt, const float* __restrict__ dinv,
                           const float* __restrict__ bias, float* __restrict__ out,
                           int do_relu) {
  __shared__ float acc[BW * ASTRIDE];   // 8448 B, stride-33 breaks bank aliasing
  int b = blockIdx.x, t = threadIdx.x;
  for (int i = t; i < BW * ASTRIDE; i += 256) acc[i] = 0.f;
  __syncthreads();
  int cnt = min(bcnt[b], CAP);
  const int* eb = bstore + (size_t)b * CAP;
  int j = t & 7;        // feature quad 0..7
  int esub = t >> 3;    // 32 edges in flight per 256-thread iteration
  for (int i = esub; i < cnt; i += 32) {
    int pk = eb[i];                       // 8 lanes same addr -> broadcast
    int src = pk >> 6, ld = pk & 63;
    float4 v = *(const float4*)(g + (size_t)src * HID + j * 4);  // coalesced 128B/edge
    float* a = &acc[ld * ASTRIDE + j * 4];
    atomicAdd(a + 0, v.x);                // ds_add_f32, fire-and-forget
    atomicAdd(a + 1, v.y);
    atomicAdd(a + 2, v.z);
    atomicAdd(a + 3, v.w);
  }
  __syncthreads();
  int node0 = b * BW;
  for (int i = t; i < BW * HID; i += 256) {
    int ld = i >> 5, f = i & 31;
    int node = node0 + ld;
    if (node < N_NODES) {
      float v = acc[ld * ASTRIDE + f] + g[(size_t)node * HID + f];  // + self-loop
      float r = dinv[node] * v + bias[f];
      if (do_relu) r = fmaxf(r, 0.f);
      out[(size_t)node * HID + f] = r;
    }
  }
}

// ---- mean-pool accumulate ----
__global__ void pool_k(const float* __restrict__ h, const int* __restrict__ batch,
                       const int* __restrict__ flag, float* __restrict__ pool,
                       float* __restrict__ cnt) {
  int idx = blockIdx.x * 256 + threadIdx.x;
  if (idx >= N_NODES * HID) return;
  int n = idx >> 5, c = idx & 31;
  int is64 = flag[0];
  int b = load_idx(batch, (long long)n, is64);
  atomicAdd(&pool[b * HID + c], h[idx]);
  if (c == 0) atomicAdd(&cnt[b], 1.0f);
}

// ---- head: out = (pool/cnt) @ Wl + bl ----
__global__ void final_k(const float* __restrict__ pool, const float* __restrict__ cnt,
                        const float* __restrict__ Wl, const float* __restrict__ bl,
                        float* __restrict__ out) {
  int i = blockIdx.x * 256 + threadIdx.x;
  if (i >= N_GRAPHS * OUT_CH) return;
  int gi = i / OUT_CH, o = i % OUT_CH;
  float c = fmaxf(cnt[gi], 1.0f);
  float acc = bl[o];
#pragma unroll
  for (int k = 0; k < HID; k++) acc += (pool[gi * HID + k] / c) * Wl[k * OUT_CH + o];
  out[i] = acc;
}

extern "C" void kernel_launch(void* const* d_in, const int* in_sizes, int n_in,
                              void* d_out, int out_size, void* d_ws, size_t ws_size,
                              hipStream_t stream) {
  const float* x   = (const float*)d_in[0];
  const int* ei    = (const int*)d_in[1];
  const int* batch = (const int*)d_in[2];
  const float* W1  = (const float*)d_in[3];
  const float* b1  = (const float*)d_in[4];
  const float* W2  = (const float*)d_in[5];
  const float* b2  = (const float*)d_in[6];
  const float* W3  = (const float*)d_in[7];
  const float* b3  = (const float*)d_in[8];
  const float* Wl  = (const float*)d_in[9];
  const float* bl  = (const float*)d_in[10];
  float* out = (float*)d_out;

  char* p = (char*)d_ws;
  auto alloc = [&](size_t bytes) {
    void* r = (void*)p;
    p += (bytes + 255) & ~(size_t)255;
    return r;
  };
  int*   bcnt   = (int*)alloc((size_t)NB * 4);
  int*   bstore = (int*)alloc((size_t)NB * CAP * 4);   // 16.0 MB
  float* dinv   = (float*)alloc((size_t)N_NODES * 4);
  int*   flag   = (int*)alloc(4);
  float* g      = (float*)alloc((size_t)N_NODES * HID * 4);
  float* h      = (float*)alloc((size_t)N_NODES * HID * 4);
  float* pool   = (float*)alloc((size_t)N_GRAPHS * HID * 4);
  float* cnt    = (float*)alloc((size_t)N_GRAPHS * 4);

  hipMemsetAsync(bcnt, 0, (size_t)NB * 4, stream);
  hipMemsetAsync(pool, 0, (size_t)N_GRAPHS * HID * 4, stream);
  hipMemsetAsync(cnt, 0, (size_t)N_GRAPHS * 4, stream);

  detect_i64<<<1, 256, 0, stream>>>(ei, flag);
  bucket_k<<<(N_EDGES + 255) / 256, 256, 0, stream>>>(ei, flag, bcnt, bstore);
  dinv_bucket_k<<<NB, 256, 0, stream>>>(bstore, bcnt, dinv);

  gemm_scale<IN_CH><<<2048, 256, 0, stream>>>(x, W1, dinv, g, N_NODES);
  agg_bucket<<<NB, 256, 0, stream>>>(g, bstore, bcnt, dinv, b1, h, 1);
  gemm_scale<HID><<<2048, 256, 0, stream>>>(h, W2, dinv, g, N_NODES);
  agg_bucket<<<NB, 256, 0, stream>>>(g, bstore, bcnt, dinv, b2, h, 1);
  gemm_scale<HID><<<2048, 256, 0, stream>>>(h, W3, dinv, g, N_NODES);
  agg_bucket<<<NB, 256, 0, stream>>>(g, bstore, bcnt, dinv, b3, h, 0);

  pool_k<<<(N_NODES * HID + 255) / 256, 256, 0, stream>>>(h, batch, flag, pool, cnt);
  final_k<<<(N_GRAPHS * OUT_CH + 255) / 256, 256, 0, stream>>>(pool, cnt, Wl, bl, out);
}

// Round 3
// 922.414 us; speedup vs baseline: 2.7093x; 2.7093x over previous
//
#include <hip/hip_runtime.h>
#include <hip/hip_bf16.h>

#define N_NODES  100000
#define N_GRAPHS 512
#define IN_CH    128
#define HID      32
#define OUT_CH   10
#define N_EDGES  3200000

#define BW       64                          // nodes per bucket
#define NB       ((N_NODES + BW - 1) / BW)   // 1563
#define CAP      2560                        // mean 2048, +11 sigma

// ---- int32/int64 index loader (low word of little-endian int64) ----
__device__ __forceinline__ int load_idx(const int* __restrict__ p, long long pos, int is64) {
  return is64 ? p[2 * pos] : p[(int)pos];
}

// Detect whether index buffers are int64 (high words of values <2^31 all zero).
__global__ void detect_i64(const int* __restrict__ ei, int* __restrict__ flag) {
  __shared__ int any_nz;
  if (threadIdx.x == 0) any_nz = 0;
  __syncthreads();
  for (int i = threadIdx.x; i < 4096; i += 256) {
    if (ei[2 * i + 1] != 0) any_nz = 1;
  }
  __syncthreads();
  if (threadIdx.x == 0) flag[0] = any_nz ? 0 : 1;
}

// ---- pass 1: bucket edges by dst>>6; store packed (src<<6 | dst&63) ----
__global__ void bucket_k(const int* __restrict__ ei, const int* __restrict__ flag,
                         int* __restrict__ bcnt, int* __restrict__ bstore) {
  int e = blockIdx.x * 256 + threadIdx.x;
  if (e >= N_EDGES) return;
  int is64 = flag[0];
  int s = load_idx(ei, (long long)e, is64);
  int d = load_idx(ei, (long long)N_EDGES + e, is64);
  int b = d >> 6;
  int pos = atomicAdd(&bcnt[b], 1);
  if (pos < CAP) bstore[(size_t)b * CAP + pos] = (s << 6) | (d & 63);
}

// ---- exclusive scan of clamped bucket counts -> global bucket bases ----
__global__ void bscan_k(const int* __restrict__ bcnt, int* __restrict__ bbase) {
  __shared__ int part[256];
  int t = threadIdx.x;
  const int CHUNK = (NB + 255) / 256;  // 7
  int v[CHUNK];
  int s = 0;
  int base = t * CHUNK;
  for (int k = 0; k < CHUNK; k++) {
    int i = base + k;
    v[k] = (i < NB) ? min(bcnt[i], CAP) : 0;
    s += v[k];
  }
  part[t] = s;
  __syncthreads();
  if (t == 0) {
    int run = 0;
    for (int i = 0; i < 256; i++) { int x = part[i]; part[i] = run; run += x; }
  }
  __syncthreads();
  int run = part[t];
  for (int k = 0; k < CHUNK; k++) {
    int i = base + k;
    if (i < NB) bbase[i] = run;
    run += v[k];
  }
}

// ---- per-bucket LDS counting sort -> per-node CSR + deg + dinv ----
__global__ void build_csr(const int* __restrict__ bstore, const int* __restrict__ bcnt,
                          const int* __restrict__ bbase, int* __restrict__ csr,
                          int* __restrict__ row_ptr, int* __restrict__ deg,
                          float* __restrict__ dinv) {
  __shared__ int hist[BW];
  __shared__ int lofs[BW];
  __shared__ int cur[BW];
  int b = blockIdx.x, t = threadIdx.x;
  if (t < BW) hist[t] = 0;
  __syncthreads();
  int cnt = min(bcnt[b], CAP);
  const int* eb = bstore + (size_t)b * CAP;
  for (int i = t; i < cnt; i += 256) atomicAdd(&hist[eb[i] & 63], 1);
  __syncthreads();
  if (t == 0) {
    int run = 0;
    for (int i = 0; i < BW; i++) { int h = hist[i]; lofs[i] = run; cur[i] = run; run += h; }
  }
  __syncthreads();
  int gbase = bbase[b];
  int node = b * BW + t;
  if (t < BW && node < N_NODES) {
    row_ptr[node] = gbase + lofs[t];
    deg[node]     = hist[t];
    dinv[node]    = rsqrtf((float)(hist[t] + 1));  // +1 self-loop
  }
  for (int i = t; i < cnt; i += 256) {
    int pk = eb[i];
    int pos = atomicAdd(&cur[pk & 63], 1);         // LDS cursor
    csr[gbase + pos] = pk >> 6;                    // dense ≤10KB region per bucket
  }
}

// ---- G = (X @ W) * dinv[row] ;  X:[n,K], W:[K,32] ----
template <int K>
__global__ void gemm_scale(const float* __restrict__ X, const float* __restrict__ W,
                           const float* __restrict__ dinv, float* __restrict__ G,
                           int nrows) {
  __shared__ float Ws[K * HID];
  __shared__ float Xs[8 * K];
  for (int i = threadIdx.x; i < K * HID; i += 256) Ws[i] = W[i];
  int c = threadIdx.x & 31, r = threadIdx.x >> 5;
  int ntiles = nrows / 8;
  for (int tile = blockIdx.x; tile < ntiles; tile += gridDim.x) {
    int row0 = tile * 8;
    __syncthreads();
    for (int i = threadIdx.x; i < 8 * K; i += 256) Xs[i] = X[row0 * K + i];
    __syncthreads();
    int row = row0 + r;
    float acc = 0.f;
#pragma unroll
    for (int k = 0; k < K; k++) acc += Xs[r * K + k] * Ws[k * 32 + c];
    G[row * 32 + c] = acc * dinv[row];
  }
}

// ---- pull aggregation, one wave per node, 8 feat-quads x 8 edges, unroll 2:
//      out[d] = act( dinv[d] * (sum_{src in N(d)} g[src] + g[d]) + bias ) ----
__global__ void agg_pull(const float* __restrict__ g, const int* __restrict__ csr,
                         const int* __restrict__ row_ptr, const int* __restrict__ deg,
                         const float* __restrict__ dinv, const float* __restrict__ bias,
                         float* __restrict__ out, int do_relu) {
  int node = blockIdx.x * 4 + (threadIdx.x >> 6);
  if (node >= N_NODES) return;
  int lane = threadIdx.x & 63;
  int j  = lane & 7;   // feature quad
  int ep = lane >> 3;  // edge-parallel group 0..7
  int start = row_ptr[node];
  int end   = start + deg[node];
  float4 a0 = {0.f, 0.f, 0.f, 0.f};
  float4 a1 = {0.f, 0.f, 0.f, 0.f};
  int i = start + ep;
  for (; i + 8 < end; i += 16) {          // 16 independent 128B gathers in flight
    int s0 = csr[i];
    int s1 = csr[i + 8];
    float4 v0 = *(const float4*)(g + (size_t)s0 * HID + j * 4);
    float4 v1 = *(const float4*)(g + (size_t)s1 * HID + j * 4);
    a0.x += v0.x; a0.y += v0.y; a0.z += v0.z; a0.w += v0.w;
    a1.x += v1.x; a1.y += v1.y; a1.z += v1.z; a1.w += v1.w;
  }
  if (i < end) {
    int s0 = csr[i];
    float4 v0 = *(const float4*)(g + (size_t)s0 * HID + j * 4);
    a0.x += v0.x; a0.y += v0.y; a0.z += v0.z; a0.w += v0.w;
  }
  a0.x += a1.x; a0.y += a1.y; a0.z += a1.z; a0.w += a1.w;
  // reduce over the 8 ep groups (lane bits 3,4,5)
#pragma unroll
  for (int m = 8; m <= 32; m <<= 1) {
    a0.x += __shfl_xor(a0.x, m, 64);
    a0.y += __shfl_xor(a0.y, m, 64);
    a0.z += __shfl_xor(a0.z, m, 64);
    a0.w += __shfl_xor(a0.w, m, 64);
  }
  if (ep == 0) {
    float4 self = *(const float4*)(g + (size_t)node * HID + j * 4);
    float4 bb   = *(const float4*)(bias + j * 4);
    float dn = dinv[node];
    float4 r;
    r.x = dn * (a0.x + self.x) + bb.x;
    r.y = dn * (a0.y + self.y) + bb.y;
    r.z = dn * (a0.z + self.z) + bb.z;
    r.w = dn * (a0.w + self.w) + bb.w;
    if (do_relu) {
      r.x = fmaxf(r.x, 0.f); r.y = fmaxf(r.y, 0.f);
      r.z = fmaxf(r.z, 0.f); r.w = fmaxf(r.w, 0.f);
    }
    *(float4*)(out + (size_t)node * HID + j * 4) = r;
  }
}

// ---- mean-pool accumulate ----
__global__ void pool_k(const float* __restrict__ h, const int* __restrict__ batch,
                       const int* __restrict__ flag, float* __restrict__ pool,
                       float* __restrict__ cnt) {
  int idx = blockIdx.x * 256 + threadIdx.x;
  if (idx >= N_NODES * HID) return;
  int n = idx >> 5, c = idx & 31;
  int is64 = flag[0];
  int b = load_idx(batch, (long long)n, is64);
  atomicAdd(&pool[b * HID + c], h[idx]);
  if (c == 0) atomicAdd(&cnt[b], 1.0f);
}

// ---- head: out = (pool/cnt) @ Wl + bl ----
__global__ void final_k(const float* __restrict__ pool, const float* __restrict__ cnt,
                        const float* __restrict__ Wl, const float* __restrict__ bl,
                        float* __restrict__ out) {
  int i = blockIdx.x * 256 + threadIdx.x;
  if (i >= N_GRAPHS * OUT_CH) return;
  int gi = i / OUT_CH, o = i % OUT_CH;
  float c = fmaxf(cnt[gi], 1.0f);
  float acc = bl[o];
#pragma unroll
  for (int k = 0; k < HID; k++) acc += (pool[gi * HID + k] / c) * Wl[k * OUT_CH + o];
  out[i] = acc;
}

extern "C" void kernel_launch(void* const* d_in, const int* in_sizes, int n_in,
                              void* d_out, int out_size, void* d_ws, size_t ws_size,
                              hipStream_t stream) {
  const float* x   = (const float*)d_in[0];
  const int* ei    = (const int*)d_in[1];
  const int* batch = (const int*)d_in[2];
  const float* W1  = (const float*)d_in[3];
  const float* b1  = (const float*)d_in[4];
  const float* W2  = (const float*)d_in[5];
  const float* b2  = (const float*)d_in[6];
  const float* W3  = (const float*)d_in[7];
  const float* b3  = (const float*)d_in[8];
  const float* Wl  = (const float*)d_in[9];
  const float* bl  = (const float*)d_in[10];
  float* out = (float*)d_out;

  char* p = (char*)d_ws;
  auto alloc = [&](size_t bytes) {
    void* r = (void*)p;
    p += (bytes + 255) & ~(size_t)255;
    return r;
  };
  int*   bcnt    = (int*)alloc((size_t)NB * 4);
  int*   bbase   = (int*)alloc((size_t)NB * 4);
  int*   bstore  = (int*)alloc((size_t)NB * CAP * 4);   // 16.0 MB
  int*   csr     = (int*)alloc((size_t)N_EDGES * 4);    // 12.8 MB
  int*   row_ptr = (int*)alloc((size_t)N_NODES * 4);
  int*   deg     = (int*)alloc((size_t)N_NODES * 4);
  float* dinv    = (float*)alloc((size_t)N_NODES * 4);
  int*   flag    = (int*)alloc(4);
  float* g       = (float*)alloc((size_t)N_NODES * HID * 4);
  float* h       = (float*)alloc((size_t)N_NODES * HID * 4);
  float* pool    = (float*)alloc((size_t)N_GRAPHS * HID * 4);
  float* cnt     = (float*)alloc((size_t)N_GRAPHS * 4);

  hipMemsetAsync(bcnt, 0, (size_t)NB * 4, stream);
  hipMemsetAsync(pool, 0, (size_t)N_GRAPHS * HID * 4, stream);
  hipMemsetAsync(cnt, 0, (size_t)N_GRAPHS * 4, stream);

  detect_i64<<<1, 256, 0, stream>>>(ei, flag);
  bucket_k<<<(N_EDGES + 255) / 256, 256, 0, stream>>>(ei, flag, bcnt, bstore);
  bscan_k<<<1, 256, 0, stream>>>(bcnt, bbase);
  build_csr<<<NB, 256, 0, stream>>>(bstore, bcnt, bbase, csr, row_ptr, deg, dinv);

  gemm_scale<IN_CH><<<2048, 256, 0, stream>>>(x, W1, dinv, g, N_NODES);
  agg_pull<<<(N_NODES + 3) / 4, 256, 0, stream>>>(g, csr, row_ptr, deg, dinv, b1, h, 1);
  gemm_scale<HID><<<2048, 256, 0, stream>>>(h, W2, dinv, g, N_NODES);
  agg_pull<<<(N_NODES + 3) / 4, 256, 0, stream>>>(g, csr, row_ptr, deg, dinv, b2, h, 1);
  gemm_scale<HID><<<2048, 256, 0, stream>>>(h, W3, dinv, g, N_NODES);
  agg_pull<<<(N_NODES + 3) / 4, 256, 0, stream>>>(g, csr, row_ptr, deg, dinv, b3, h, 0);

  pool_k<<<(N_NODES * HID + 255) / 256, 256, 0, stream>>>(h, batch, flag, pool, cnt);
  final_k<<<(N_GRAPHS * OUT_CH + 255) / 256, 256, 0, stream>>>(pool, cnt, Wl, bl, out);
}

// Round 4
// 492.089 us; speedup vs baseline: 5.0786x; 1.8745x over previous
//
#include <hip/hip_runtime.h>
#include <hip/hip_bf16.h>

#define N_NODES  100000
#define N_GRAPHS 512
#define IN_CH    128
#define HID      32
#define OUT_CH   10
#define N_EDGES  3200000

#define SZC   256                            // nodes per bucket
#define NBC   ((N_NODES + SZC - 1) / SZC)    // 391
#define CAPC  9216                           // mean 8192, +11 sigma
#define RND   8192                           // edges per binning round
#define EPT   32                             // edges per thread per round
#define NRND  ((N_EDGES + RND - 1) / RND)    // 391

// ---- int32/int64 index loader (low word of little-endian int64) ----
__device__ __forceinline__ int load_idx(const int* __restrict__ p, long long pos, int is64) {
  return is64 ? p[2 * pos] : p[(int)pos];
}

// Detect whether index buffers are int64 (high words of values <2^31 all zero).
__global__ void detect_i64(const int* __restrict__ ei, int* __restrict__ flag) {
  __shared__ int any_nz;
  if (threadIdx.x == 0) any_nz = 0;
  __syncthreads();
  for (int i = threadIdx.x; i < 4096; i += 256) {
    if (ei[2 * i + 1] != 0) any_nz = 1;
  }
  __syncthreads();
  if (threadIdx.x == 0) flag[0] = any_nz ? 0 : 1;
}

// ---- pass 1: round-based binning with per-round contiguous run reservation.
//      Each block: 8192 edges -> LDS hist over 391 buckets -> 1 global
//      atomicAdd per touched bucket reserves a dense run -> LDS-cursor scatter.
//      Runs are written by ONE CU into consecutive addresses => lines fill. ----
__global__ void bucket_k(const int* __restrict__ ei, const int* __restrict__ flag,
                         int* __restrict__ gcur, int* __restrict__ bstore) {
  __shared__ int hist[NBC];
  __shared__ int base[NBC];
  int is64 = flag[0];
  int t = threadIdx.x;
  for (int rd = blockIdx.x; rd < NRND; rd += gridDim.x) {
    for (int i = t; i < NBC; i += 256) hist[i] = 0;
    __syncthreads();
    long long e0 = (long long)rd * RND;
    int   pk[EPT];
    short cb[EPT];
#pragma unroll
    for (int k = 0; k < EPT; k++) {
      long long e = e0 + k * 256 + t;
      if (e < N_EDGES) {
        int s = load_idx(ei, e, is64);
        int d = load_idx(ei, N_EDGES + e, is64);
        pk[k] = (s << 8) | (d & 255);
        cb[k] = (short)(d >> 8);
        atomicAdd(&hist[d >> 8], 1);
      } else {
        cb[k] = -1;
      }
    }
    __syncthreads();
    for (int c = t; c < NBC; c += 256) {
      int h = hist[c];
      if (h > 0) base[c] = atomicAdd(&gcur[c], h);
    }
    __syncthreads();
#pragma unroll
    for (int k = 0; k < EPT; k++) {
      if (cb[k] >= 0) {
        int c = cb[k];
        int pos = atomicAdd(&base[c], 1);        // LDS cursor from global base
        if (pos < CAPC) bstore[(size_t)c * CAPC + pos] = pk[k];
      }
    }
    __syncthreads();
  }
}

// ---- exclusive scan of clamped coarse-bucket counts -> global bases ----
__global__ void bscan_k(const int* __restrict__ gcur, int* __restrict__ bbase) {
  __shared__ int part[256];
  int t = threadIdx.x;
  const int CHUNK = (NBC + 255) / 256;  // 2
  int v[CHUNK];
  int s = 0;
  int base = t * CHUNK;
  for (int k = 0; k < CHUNK; k++) {
    int i = base + k;
    v[k] = (i < NBC) ? min(gcur[i], CAPC) : 0;
    s += v[k];
  }
  part[t] = s;
  __syncthreads();
  if (t == 0) {
    int run = 0;
    for (int i = 0; i < 256; i++) { int x = part[i]; part[i] = run; run += x; }
  }
  __syncthreads();
  int run = part[t];
  for (int k = 0; k < CHUNK; k++) {
    int i = base + k;
    if (i < NBC) bbase[i] = run;
    run += v[k];
  }
}

// ---- per-bucket LDS counting sort -> per-node CSR + deg + dinv ----
__global__ void build_csr(const int* __restrict__ bstore, const int* __restrict__ gcur,
                          const int* __restrict__ bbase, int* __restrict__ csr,
                          int* __restrict__ row_ptr, int* __restrict__ deg,
                          float* __restrict__ dinv) {
  __shared__ int hist[SZC];
  __shared__ int sc[SZC];
  __shared__ int cur[SZC];
  int b = blockIdx.x, t = threadIdx.x;
  hist[t] = 0;
  __syncthreads();
  int cnt = min(gcur[b], CAPC);
  const int* eb = bstore + (size_t)b * CAPC;
  for (int i = t; i < cnt; i += 256) atomicAdd(&hist[eb[i] & 255], 1);
  __syncthreads();
  int own = hist[t];
  sc[t] = own;
  __syncthreads();
  for (int off = 1; off < SZC; off <<= 1) {
    int u = (t >= off) ? sc[t - off] : 0;
    __syncthreads();
    sc[t] += u;
    __syncthreads();
  }
  int excl = sc[t] - own;
  int gbase = bbase[b];
  int node = b * SZC + t;
  if (node < N_NODES) {
    row_ptr[node] = gbase + excl;
    deg[node]     = own;
    dinv[node]    = rsqrtf((float)(own + 1));  // +1 self-loop
  }
  cur[t] = excl;
  __syncthreads();
  for (int i = t; i < cnt; i += 256) {
    int pk = eb[i];                              // L2-hot (same block re-read)
    int pos = atomicAdd(&cur[pk & 255], 1);
    csr[gbase + pos] = pk >> 8;                  // dense ~33KB region, L2-resident
  }
}

// ---- G = (X @ W) * dinv[row] ;  X:[n,K], W:[K,32] ----
template <int K>
__global__ void gemm_scale(const float* __restrict__ X, const float* __restrict__ W,
                           const float* __restrict__ dinv, float* __restrict__ G,
                           int nrows) {
  __shared__ float Ws[K * HID];
  __shared__ float Xs[8 * K];
  for (int i = threadIdx.x; i < K * HID; i += 256) Ws[i] = W[i];
  int c = threadIdx.x & 31, r = threadIdx.x >> 5;
  int ntiles = nrows / 8;
  for (int tile = blockIdx.x; tile < ntiles; tile += gridDim.x) {
    int row0 = tile * 8;
    __syncthreads();
    for (int i = threadIdx.x; i < 8 * K; i += 256) Xs[i] = X[row0 * K + i];
    __syncthreads();
    int row = row0 + r;
    float acc = 0.f;
#pragma unroll
    for (int k = 0; k < K; k++) acc += Xs[r * K + k] * Ws[k * 32 + c];
    G[row * 32 + c] = acc * dinv[row];
  }
}

// ---- pull aggregation, one wave per node, 8 feat-quads x 8 edges, unroll 2:
//      out[d] = act( dinv[d] * (sum_{src in N(d)} g[src] + g[d]) + bias ) ----
__global__ void agg_pull(const float* __restrict__ g, const int* __restrict__ csr,
                         const int* __restrict__ row_ptr, const int* __restrict__ deg,
                         const float* __restrict__ dinv, const float* __restrict__ bias,
                         float* __restrict__ out, int do_relu) {
  int node = blockIdx.x * 4 + (threadIdx.x >> 6);
  if (node >= N_NODES) return;
  int lane = threadIdx.x & 63;
  int j  = lane & 7;   // feature quad
  int ep = lane >> 3;  // edge-parallel group 0..7
  int start = row_ptr[node];
  int end   = start + deg[node];
  float4 a0 = {0.f, 0.f, 0.f, 0.f};
  float4 a1 = {0.f, 0.f, 0.f, 0.f};
  int i = start + ep;
  for (; i + 8 < end; i += 16) {          // 16 independent 128B gathers in flight
    int s0 = csr[i];
    int s1 = csr[i + 8];
    float4 v0 = *(const float4*)(g + (size_t)s0 * HID + j * 4);
    float4 v1 = *(const float4*)(g + (size_t)s1 * HID + j * 4);
    a0.x += v0.x; a0.y += v0.y; a0.z += v0.z; a0.w += v0.w;
    a1.x += v1.x; a1.y += v1.y; a1.z += v1.z; a1.w += v1.w;
  }
  if (i < end) {
    int s0 = csr[i];
    float4 v0 = *(const float4*)(g + (size_t)s0 * HID + j * 4);
    a0.x += v0.x; a0.y += v0.y; a0.z += v0.z; a0.w += v0.w;
  }
  a0.x += a1.x; a0.y += a1.y; a0.z += a1.z; a0.w += a1.w;
#pragma unroll
  for (int m = 8; m <= 32; m <<= 1) {
    a0.x += __shfl_xor(a0.x, m, 64);
    a0.y += __shfl_xor(a0.y, m, 64);
    a0.z += __shfl_xor(a0.z, m, 64);
    a0.w += __shfl_xor(a0.w, m, 64);
  }
  if (ep == 0) {
    float4 self = *(const float4*)(g + (size_t)node * HID + j * 4);
    float4 bb   = *(const float4*)(bias + j * 4);
    float dn = dinv[node];
    float4 r;
    r.x = dn * (a0.x + self.x) + bb.x;
    r.y = dn * (a0.y + self.y) + bb.y;
    r.z = dn * (a0.z + self.z) + bb.z;
    r.w = dn * (a0.w + self.w) + bb.w;
    if (do_relu) {
      r.x = fmaxf(r.x, 0.f); r.y = fmaxf(r.y, 0.f);
      r.z = fmaxf(r.z, 0.f); r.w = fmaxf(r.w, 0.f);
    }
    *(float4*)(out + (size_t)node * HID + j * 4) = r;
  }
}

// ---- mean-pool accumulate ----
__global__ void pool_k(const float* __restrict__ h, const int* __restrict__ batch,
                       const int* __restrict__ flag, float* __restrict__ pool,
                       float* __restrict__ cnt) {
  int idx = blockIdx.x * 256 + threadIdx.x;
  if (idx >= N_NODES * HID) return;
  int n = idx >> 5, c = idx & 31;
  int is64 = flag[0];
  int b = load_idx(batch, (long long)n, is64);
  atomicAdd(&pool[b * HID + c], h[idx]);
  if (c == 0) atomicAdd(&cnt[b], 1.0f);
}

// ---- head: out = (pool/cnt) @ Wl + bl ----
__global__ void final_k(const float* __restrict__ pool, const float* __restrict__ cnt,
                        const float* __restrict__ Wl, const float* __restrict__ bl,
                        float* __restrict__ out) {
  int i = blockIdx.x * 256 + threadIdx.x;
  if (i >= N_GRAPHS * OUT_CH) return;
  int gi = i / OUT_CH, o = i % OUT_CH;
  float c = fmaxf(cnt[gi], 1.0f);
  float acc = bl[o];
#pragma unroll
  for (int k = 0; k < HID; k++) acc += (pool[gi * HID + k] / c) * Wl[k * OUT_CH + o];
  out[i] = acc;
}

extern "C" void kernel_launch(void* const* d_in, const int* in_sizes, int n_in,
                              void* d_out, int out_size, void* d_ws, size_t ws_size,
                              hipStream_t stream) {
  const float* x   = (const float*)d_in[0];
  const int* ei    = (const int*)d_in[1];
  const int* batch = (const int*)d_in[2];
  const float* W1  = (const float*)d_in[3];
  const float* b1  = (const float*)d_in[4];
  const float* W2  = (const float*)d_in[5];
  const float* b2  = (const float*)d_in[6];
  const float* W3  = (const float*)d_in[7];
  const float* b3  = (const float*)d_in[8];
  const float* Wl  = (const float*)d_in[9];
  const float* bl  = (const float*)d_in[10];
  float* out = (float*)d_out;

  char* p = (char*)d_ws;
  auto alloc = [&](size_t bytes) {
    void* r = (void*)p;
    p += (bytes + 255) & ~(size_t)255;
    return r;
  };
  int*   gcur    = (int*)alloc((size_t)NBC * 4);
  int*   bbase   = (int*)alloc((size_t)NBC * 4);
  int*   bstore  = (int*)alloc((size_t)NBC * CAPC * 4);  // 14.4 MB
  int*   csr     = (int*)alloc((size_t)N_EDGES * 4);     // 12.8 MB
  int*   row_ptr = (int*)alloc((size_t)N_NODES * 4);
  int*   deg     = (int*)alloc((size_t)N_NODES * 4);
  float* dinv    = (float*)alloc((size_t)N_NODES * 4);
  int*   flag    = (int*)alloc(4);
  float* g       = (float*)alloc((size_t)N_NODES * HID * 4);
  float* h       = (float*)alloc((size_t)N_NODES * HID * 4);
  float* pool    = (float*)alloc((size_t)N_GRAPHS * HID * 4);
  float* cnt     = (float*)alloc((size_t)N_GRAPHS * 4);

  hipMemsetAsync(gcur, 0, (size_t)NBC * 4, stream);
  hipMemsetAsync(pool, 0, (size_t)N_GRAPHS * HID * 4, stream);
  hipMemsetAsync(cnt, 0, (size_t)N_GRAPHS * 4, stream);

  detect_i64<<<1, 256, 0, stream>>>(ei, flag);
  bucket_k<<<NRND, 256, 0, stream>>>(ei, flag, gcur, bstore);
  bscan_k<<<1, 256, 0, stream>>>(gcur, bbase);
  build_csr<<<NBC, 256, 0, stream>>>(bstore, gcur, bbase, csr, row_ptr, deg, dinv);

  gemm_scale<IN_CH><<<2048, 256, 0, stream>>>(x, W1, dinv, g, N_NODES);
  agg_pull<<<(N_NODES + 3) / 4, 256, 0, stream>>>(g, csr, row_ptr, deg, dinv, b1, h, 1);
  gemm_scale<HID><<<2048, 256, 0, stream>>>(h, W2, dinv, g, N_NODES);
  agg_pull<<<(N_NODES + 3) / 4, 256, 0, stream>>>(g, csr, row_ptr, deg, dinv, b2, h, 1);
  gemm_scale<HID><<<2048, 256, 0, stream>>>(h, W3, dinv, g, N_NODES);
  agg_pull<<<(N_NODES + 3) / 4, 256, 0, stream>>>(g, csr, row_ptr, deg, dinv, b3, h, 0);

  pool_k<<<(N_NODES * HID + 255) / 256, 256, 0, stream>>>(h, batch, flag, pool, cnt);
  final_k<<<(N_GRAPHS * OUT_CH + 255) / 256, 256, 0, stream>>>(pool, cnt, Wl, bl, out);
}

// Round 5
// 344.487 us; speedup vs baseline: 7.2547x; 1.4285x over previous
//
#include <hip/hip_runtime.h>
#include <hip/hip_bf16.h>

#define N_NODES  100000
#define N_GRAPHS 512
#define IN_CH    128
#define HID      32
#define OUT_CH   10
#define N_EDGES  3200000

#define SZC   256                            // nodes per bucket
#define NBC   ((N_NODES + SZC - 1) / SZC)    // 391
#define CAPC  9216                           // mean 8192, +11 sigma
#define RND   8192                           // edges per binning round
#define EPT   32                             // edges per thread per round
#define NRND  ((N_EDGES + RND - 1) / RND)    // 391

// ---- int32/int64 index loader (low word of little-endian int64) ----
__device__ __forceinline__ int load_idx(const int* __restrict__ p, long long pos, int is64) {
  return is64 ? p[2 * pos] : p[(int)pos];
}

// Detect whether an index buffer is int64 (high words of values <2^31 all zero).
// For int32 data the sampled odd words are later values (nonzero for edge ids
// and for sorted batch past graph 0).
__global__ void detect_i64(const int* __restrict__ buf, int* __restrict__ flag) {
  __shared__ int any_nz;
  if (threadIdx.x == 0) any_nz = 0;
  __syncthreads();
  for (int i = threadIdx.x; i < 4096; i += 256) {
    if (buf[2 * i + 1] != 0) any_nz = 1;
  }
  __syncthreads();
  if (threadIdx.x == 0) flag[0] = any_nz ? 0 : 1;
}

// ---- pass 1: round-based binning with per-round contiguous run reservation ----
__global__ void bucket_k(const int* __restrict__ ei, const int* __restrict__ flag,
                         int* __restrict__ gcur, int* __restrict__ bstore) {
  __shared__ int hist[NBC];
  __shared__ int base[NBC];
  int is64 = flag[0];
  int t = threadIdx.x;
  for (int rd = blockIdx.x; rd < NRND; rd += gridDim.x) {
    for (int i = t; i < NBC; i += 256) hist[i] = 0;
    __syncthreads();
    long long e0 = (long long)rd * RND;
    int   pk[EPT];
    short cb[EPT];
#pragma unroll
    for (int k = 0; k < EPT; k++) {
      long long e = e0 + k * 256 + t;
      if (e < N_EDGES) {
        int s = load_idx(ei, e, is64);
        int d = load_idx(ei, N_EDGES + e, is64);
        pk[k] = (s << 8) | (d & 255);
        cb[k] = (short)(d >> 8);
        atomicAdd(&hist[d >> 8], 1);
      } else {
        cb[k] = -1;
      }
    }
    __syncthreads();
    for (int c = t; c < NBC; c += 256) {
      int h = hist[c];
      if (h > 0) base[c] = atomicAdd(&gcur[c], h);
    }
    __syncthreads();
#pragma unroll
    for (int k = 0; k < EPT; k++) {
      if (cb[k] >= 0) {
        int c = cb[k];
        int pos = atomicAdd(&base[c], 1);        // LDS cursor from global base
        if (pos < CAPC) bstore[(size_t)c * CAPC + pos] = pk[k];
      }
    }
    __syncthreads();
  }
}

// ---- exclusive scan of clamped coarse-bucket counts -> global bases ----
__global__ void bscan_k(const int* __restrict__ gcur, int* __restrict__ bbase) {
  __shared__ int part[256];
  int t = threadIdx.x;
  const int CHUNK = (NBC + 255) / 256;  // 2
  int v[CHUNK];
  int s = 0;
  int base = t * CHUNK;
  for (int k = 0; k < CHUNK; k++) {
    int i = base + k;
    v[k] = (i < NBC) ? min(gcur[i], CAPC) : 0;
    s += v[k];
  }
  part[t] = s;
  __syncthreads();
  if (t == 0) {
    int run = 0;
    for (int i = 0; i < 256; i++) { int x = part[i]; part[i] = run; run += x; }
  }
  __syncthreads();
  int run = part[t];
  for (int k = 0; k < CHUNK; k++) {
    int i = base + k;
    if (i < NBC) bbase[i] = run;
    run += v[k];
  }
}

// ---- per-bucket LDS counting sort -> per-node CSR + deg + dinv ----
__global__ void build_csr(const int* __restrict__ bstore, const int* __restrict__ gcur,
                          const int* __restrict__ bbase, int* __restrict__ csr,
                          int* __restrict__ row_ptr, int* __restrict__ deg,
                          float* __restrict__ dinv) {
  __shared__ int hist[SZC];
  __shared__ int sc[SZC];
  __shared__ int cur[SZC];
  int b = blockIdx.x, t = threadIdx.x;
  hist[t] = 0;
  __syncthreads();
  int cnt = min(gcur[b], CAPC);
  const int* eb = bstore + (size_t)b * CAPC;
  for (int i = t; i < cnt; i += 256) atomicAdd(&hist[eb[i] & 255], 1);
  __syncthreads();
  int own = hist[t];
  sc[t] = own;
  __syncthreads();
  for (int off = 1; off < SZC; off <<= 1) {
    int u = (t >= off) ? sc[t - off] : 0;
    __syncthreads();
    sc[t] += u;
    __syncthreads();
  }
  int excl = sc[t] - own;
  int gbase = bbase[b];
  int node = b * SZC + t;
  if (node < N_NODES) {
    row_ptr[node] = gbase + excl;
    deg[node]     = own;
    dinv[node]    = rsqrtf((float)(own + 1));  // +1 self-loop
  }
  cur[t] = excl;
  __syncthreads();
  for (int i = t; i < cnt; i += 256) {
    int pk = eb[i];                              // L2-hot (same block re-read)
    int pos = atomicAdd(&cur[pk & 255], 1);
    csr[gbase + pos] = pk >> 8;                  // dense ~33KB region, L2-resident
  }
}

// ---- G = (X @ W) * dinv[row] ;  X:[n,K], W:[K,32] ----
template <int K>
__global__ void gemm_scale(const float* __restrict__ X, const float* __restrict__ W,
                           const float* __restrict__ dinv, float* __restrict__ G,
                           int nrows) {
  __shared__ float Ws[K * HID];
  __shared__ float Xs[8 * K];
  for (int i = threadIdx.x; i < K * HID; i += 256) Ws[i] = W[i];
  int c = threadIdx.x & 31, r = threadIdx.x >> 5;
  int ntiles = nrows / 8;
  for (int tile = blockIdx.x; tile < ntiles; tile += gridDim.x) {
    int row0 = tile * 8;
    __syncthreads();
    for (int i = threadIdx.x; i < 8 * K; i += 256) Xs[i] = X[row0 * K + i];
    __syncthreads();
    int row = row0 + r;
    float acc = 0.f;
#pragma unroll
    for (int k = 0; k < K; k++) acc += Xs[r * K + k] * Ws[k * 32 + c];
    G[row * 32 + c] = acc * dinv[row];
  }
}

// ---- pull aggregation, one wave per node, 8 feat-quads x 8 edges, unroll 2 ----
__global__ void agg_pull(const float* __restrict__ g, const int* __restrict__ csr,
                         const int* __restrict__ row_ptr, const int* __restrict__ deg,
                         const float* __restrict__ dinv, const float* __restrict__ bias,
                         float* __restrict__ out, int do_relu) {
  int node = blockIdx.x * 4 + (threadIdx.x >> 6);
  if (node >= N_NODES) return;
  int lane = threadIdx.x & 63;
  int j  = lane & 7;   // feature quad
  int ep = lane >> 3;  // edge-parallel group 0..7
  int start = row_ptr[node];
  int end   = start + deg[node];
  float4 a0 = {0.f, 0.f, 0.f, 0.f};
  float4 a1 = {0.f, 0.f, 0.f, 0.f};
  int i = start + ep;
  for (; i + 8 < end; i += 16) {          // 16 independent 128B gathers in flight
    int s0 = csr[i];
    int s1 = csr[i + 8];
    float4 v0 = *(const float4*)(g + (size_t)s0 * HID + j * 4);
    float4 v1 = *(const float4*)(g + (size_t)s1 * HID + j * 4);
    a0.x += v0.x; a0.y += v0.y; a0.z += v0.z; a0.w += v0.w;
    a1.x += v1.x; a1.y += v1.y; a1.z += v1.z; a1.w += v1.w;
  }
  if (i < end) {
    int s0 = csr[i];
    float4 v0 = *(const float4*)(g + (size_t)s0 * HID + j * 4);
    a0.x += v0.x; a0.y += v0.y; a0.z += v0.z; a0.w += v0.w;
  }
  a0.x += a1.x; a0.y += a1.y; a0.z += a1.z; a0.w += a1.w;
#pragma unroll
  for (int m = 8; m <= 32; m <<= 1) {
    a0.x += __shfl_xor(a0.x, m, 64);
    a0.y += __shfl_xor(a0.y, m, 64);
    a0.z += __shfl_xor(a0.z, m, 64);
    a0.w += __shfl_xor(a0.w, m, 64);
  }
  if (ep == 0) {
    float4 self = *(const float4*)(g + (size_t)node * HID + j * 4);
    float4 bb   = *(const float4*)(bias + j * 4);
    float dn = dinv[node];
    float4 r;
    r.x = dn * (a0.x + self.x) + bb.x;
    r.y = dn * (a0.y + self.y) + bb.y;
    r.z = dn * (a0.z + self.z) + bb.z;
    r.w = dn * (a0.w + self.w) + bb.w;
    if (do_relu) {
      r.x = fmaxf(r.x, 0.f); r.y = fmaxf(r.y, 0.f);
      r.z = fmaxf(r.z, 0.f); r.w = fmaxf(r.w, 0.f);
    }
    *(float4*)(out + (size_t)node * HID + j * 4) = r;
  }
}

// ---- fused mean-pool + linear head; batch is SORTED so graph g owns a
//      contiguous node range found by binary search. Zero atomics. ----
__global__ void pool_head(const float* __restrict__ h, const int* __restrict__ batch,
                          const int* __restrict__ bflag, const float* __restrict__ Wl,
                          const float* __restrict__ bl, float* __restrict__ out) {
  __shared__ float acc[8][HID];
  int g = blockIdx.x, t = threadIdx.x;
  int is64 = bflag[0];
  // lower_bound(target): first idx with batch[idx] >= target (wave-uniform)
  int start, end;
  {
    int lo = 0, hi = N_NODES;
    while (lo < hi) { int m = (lo + hi) >> 1; if (load_idx(batch, m, is64) < g) lo = m + 1; else hi = m; }
    start = lo;
    lo = start; hi = N_NODES;
    while (lo < hi) { int m = (lo + hi) >> 1; if (load_idx(batch, m, is64) < g + 1) lo = m + 1; else hi = m; }
    end = lo;
  }
  int c = t & 31, r = t >> 5;
  float s = 0.f;
  for (int i = start + r; i < end; i += 8) s += h[(size_t)i * HID + c];
  acc[r][c] = s;
  __syncthreads();
  if (t < HID) {
    float v = 0.f;
#pragma unroll
    for (int q = 0; q < 8; q++) v += acc[q][t];
    acc[0][t] = v / fmaxf((float)(end - start), 1.0f);
  }
  __syncthreads();
  if (t < OUT_CH) {
    float o = bl[t];
#pragma unroll
    for (int k = 0; k < HID; k++) o += acc[0][k] * Wl[k * OUT_CH + t];
    out[g * OUT_CH + t] = o;
  }
}

extern "C" void kernel_launch(void* const* d_in, const int* in_sizes, int n_in,
                              void* d_out, int out_size, void* d_ws, size_t ws_size,
                              hipStream_t stream) {
  const float* x   = (const float*)d_in[0];
  const int* ei    = (const int*)d_in[1];
  const int* batch = (const int*)d_in[2];
  const float* W1  = (const float*)d_in[3];
  const float* b1  = (const float*)d_in[4];
  const float* W2  = (const float*)d_in[5];
  const float* b2  = (const float*)d_in[6];
  const float* W3  = (const float*)d_in[7];
  const float* b3  = (const float*)d_in[8];
  const float* Wl  = (const float*)d_in[9];
  const float* bl  = (const float*)d_in[10];
  float* out = (float*)d_out;

  char* p = (char*)d_ws;
  auto alloc = [&](size_t bytes) {
    void* r = (void*)p;
    p += (bytes + 255) & ~(size_t)255;
    return r;
  };
  int*   gcur    = (int*)alloc((size_t)NBC * 4);
  int*   bbase   = (int*)alloc((size_t)NBC * 4);
  int*   bstore  = (int*)alloc((size_t)NBC * CAPC * 4);  // 14.4 MB
  int*   csr     = (int*)alloc((size_t)N_EDGES * 4);     // 12.8 MB
  int*   row_ptr = (int*)alloc((size_t)N_NODES * 4);
  int*   deg     = (int*)alloc((size_t)N_NODES * 4);
  float* dinv    = (float*)alloc((size_t)N_NODES * 4);
  int*   flag    = (int*)alloc(4);
  int*   bflag   = (int*)alloc(4);
  float* g       = (float*)alloc((size_t)N_NODES * HID * 4);
  float* h       = (float*)alloc((size_t)N_NODES * HID * 4);

  hipMemsetAsync(gcur, 0, (size_t)NBC * 4, stream);

  detect_i64<<<1, 256, 0, stream>>>(ei, flag);
  detect_i64<<<1, 256, 0, stream>>>(batch, bflag);
  bucket_k<<<NRND, 256, 0, stream>>>(ei, flag, gcur, bstore);
  bscan_k<<<1, 256, 0, stream>>>(gcur, bbase);
  build_csr<<<NBC, 256, 0, stream>>>(bstore, gcur, bbase, csr, row_ptr, deg, dinv);

  gemm_scale<IN_CH><<<2048, 256, 0, stream>>>(x, W1, dinv, g, N_NODES);
  agg_pull<<<(N_NODES + 3) / 4, 256, 0, stream>>>(g, csr, row_ptr, deg, dinv, b1, h, 1);
  gemm_scale<HID><<<2048, 256, 0, stream>>>(h, W2, dinv, g, N_NODES);
  agg_pull<<<(N_NODES + 3) / 4, 256, 0, stream>>>(g, csr, row_ptr, deg, dinv, b2, h, 1);
  gemm_scale<HID><<<2048, 256, 0, stream>>>(h, W3, dinv, g, N_NODES);
  agg_pull<<<(N_NODES + 3) / 4, 256, 0, stream>>>(g, csr, row_ptr, deg, dinv, b3, h, 0);

  pool_head<<<N_GRAPHS, 256, 0, stream>>>(h, batch, bflag, Wl, bl, out);
}